// Round 7
// baseline (285.561 us; speedup 1.0000x reference)
//
#include <hip/hip_runtime.h>

typedef __bf16 bf16;
typedef bf16 bf16x8 __attribute__((ext_vector_type(8)));
typedef bf16 bf16x4 __attribute__((ext_vector_type(4)));
typedef bf16 bf16x2 __attribute__((ext_vector_type(2)));
typedef float f32x4 __attribute__((ext_vector_type(4)));
typedef float f32x16 __attribute__((ext_vector_type(16)));
typedef unsigned int u32;
typedef u32 u32x4 __attribute__((ext_vector_type(4)));

constexpr int Bb = 4, Ss = 2048, Dd = 1024, NH = 16, HD = 64;
constexpr int BS = Bb * Ss;          // 8192
constexpr float CSC = 0.18033688011112042f;  // (1/sqrt(64)) * log2(e), folded into Wq

__device__ __forceinline__ int sw(int row, int col) {
  return (row << 6) + (col ^ ((row & 7) << 3));
}

__device__ __forceinline__ void g2l16(const bf16* g, bf16* l) {
  __builtin_amdgcn_global_load_lds(
      (const __attribute__((address_space(1))) void*)g,
      (__attribute__((address_space(3))) void*)l, 16, 0, 0);
}

__device__ __forceinline__ u32 pkbf(float a, float b) {
  bf16x2 v = {(bf16)a, (bf16)b};
  return __builtin_bit_cast(u32, v);
}

// ---------------- prep: x cvt + weight transposes + bias ----------------
__global__ void prep(const float* __restrict__ x, bf16* __restrict__ xb,
                     const float* __restrict__ Wq, const float* __restrict__ Wk,
                     const float* __restrict__ Wv, const float* __restrict__ Wo,
                     const float* __restrict__ bq, const float* __restrict__ bk,
                     const float* __restrict__ bv,
                     bf16* __restrict__ WT_all, bf16* __restrict__ WoT,
                     float* __restrict__ bias_all) {
  __shared__ bf16 Ts[64 * 72];
  const int t = threadIdx.x;
  if (blockIdx.y == 0) {           // x: f32 -> bf16 (8192 blocks)
    int o = (blockIdx.x * 256 + t) * 4;
    f32x4 v = *(const f32x4*)&x[o];
    bf16x4 r = {(bf16)v[0], (bf16)v[1], (bf16)v[2], (bf16)v[3]};
    *(bf16x4*)&xb[o] = r;
    return;
  }
  if (blockIdx.x > 1024) return;
  if (blockIdx.x == 1024) {
    for (int j = t; j < 3072; j += 256) {
      int s2 = j >> 10;
      const float* bb = (s2 == 0) ? bq : (s2 == 1) ? bk : bv;
      bias_all[j] = bb[j & 1023] * (s2 == 0 ? CSC : 1.0f);
    }
    return;
  }
  const int sel = blockIdx.x >> 8, bx = blockIdx.x & 255;
  if (sel < 3) {
    const float* W = (sel == 0) ? Wq : (sel == 1) ? Wk : Wv;
    float scale = (sel == 0) ? CSC : 1.0f;
    int head = bx >> 4, dt = bx & 15;
    const float* src = W + head * 65536 + dt * 64 * 64;   // [64 d][64 h]
#pragma unroll
    for (int i = 0; i < 4; ++i) {
      int idx = i * 256 + t;
      int dr = idx >> 4, hc = (idx & 15) * 4;
      f32x4 v = *(const f32x4*)&src[dr * 64 + hc];
#pragma unroll
      for (int k = 0; k < 4; ++k) Ts[(hc + k) * 72 + dr] = (bf16)(v[k] * scale);
    }
    __syncthreads();
    bf16* dst = WT_all + (size_t)sel * 1048576 + (size_t)(head * 64) * 1024 + dt * 64;
#pragma unroll
    for (int i = 0; i < 2; ++i) {
      int idx = i * 256 + t;
      int hr = idx >> 3, ch = (idx & 7) * 8;
      *(bf16x8*)&dst[(size_t)hr * 1024 + ch] = *(const bf16x8*)&Ts[hr * 72 + ch];
    }
  } else {
    int ct = bx >> 4, dt = bx & 15;
    const float* src = Wo + (size_t)(ct * 64) * 1024 + dt * 64;
#pragma unroll
    for (int i = 0; i < 4; ++i) {
      int idx = i * 256 + t;
      int cr = idx >> 4, dc = (idx & 15) * 4;
      f32x4 v = *(const f32x4*)&src[(size_t)cr * 1024 + dc];
#pragma unroll
      for (int k = 0; k < 4; ++k) Ts[(dc + k) * 72 + cr] = (bf16)v[k];
    }
    __syncthreads();
    bf16* dst = WoT + (size_t)(dt * 64) * 1024 + ct * 64;
#pragma unroll
    for (int i = 0; i < 2; ++i) {
      int idx = i * 256 + t;
      int dr = idx >> 3, ch = (idx & 7) * 8;
      *(bf16x8*)&dst[(size_t)dr * 1024 + ch] = *(const bf16x8*)&Ts[dr * 72 + ch];
    }
  }
}

// ---------------- shared 128x128 K=1024 MFMA core ----------------
__device__ __forceinline__ void gemm_core(const bf16* __restrict__ A,
                                          const bf16* __restrict__ BT,
                                          int m0, int n0, bf16* As, bf16* Bs,
                                          f32x4 (&acc)[4][4]) {
  const int t = threadIdx.x;
  const int l = t & 63, q = l >> 4, lm = l & 15;
  const int w = t >> 6, wm = w & 1, wn = w >> 1;
  int ro[4], co[4];
#pragma unroll
  for (int i = 0; i < 4; ++i) {
    int o = i * 256 + t;
    ro[i] = o >> 3;
    co[i] = ((o & 7) ^ ((o >> 3) & 7)) << 3;
  }
  const int lbase = (t & 192) * 8;
  for (int k0 = 0; k0 < 1024; k0 += 64) {
    __syncthreads();
#pragma unroll
    for (int i = 0; i < 4; ++i)
      g2l16(&A[(size_t)(m0 + ro[i]) * 1024 + k0 + co[i]], &As[i * 2048 + lbase]);
#pragma unroll
    for (int i = 0; i < 4; ++i)
      g2l16(&BT[(size_t)(n0 + ro[i]) * 1024 + k0 + co[i]], &Bs[i * 2048 + lbase]);
    __syncthreads();
#pragma unroll
    for (int kh = 0; kh < 2; ++kh) {
      bf16x8 a[4], b[4];
#pragma unroll
      for (int i = 0; i < 4; ++i)
        a[i] = *(const bf16x8*)&As[sw(wm * 64 + i * 16 + lm, kh * 32 + q * 8)];
#pragma unroll
      for (int i = 0; i < 4; ++i)
        b[i] = *(const bf16x8*)&Bs[sw(wn * 64 + i * 16 + lm, kh * 32 + q * 8)];
#pragma unroll
      for (int mt = 0; mt < 4; ++mt)
#pragma unroll
        for (int nt = 0; nt < 4; ++nt)
          acc[mt][nt] = __builtin_amdgcn_mfma_f32_16x16x32_bf16(a[mt], b[nt], acc[mt][nt], 0, 0, 0);
    }
  }
}

// ---------------- fused QK + V GEMM (1536 blocks) ----------------
__global__ __launch_bounds__(256) void gemm_qkv(const bf16* __restrict__ xb,
                                                const bf16* __restrict__ WT,
                                                const float* __restrict__ bias_all,
                                                bf16* __restrict__ QKb,
                                                bf16* __restrict__ VTb) {
  __shared__ __align__(16) bf16 As[128 * 64];
  __shared__ __align__(16) bf16 Bs[128 * 64];
  const int bid = blockIdx.x;
  const int t = threadIdx.x;
  const int l = t & 63, q = l >> 4, lm = l & 15;
  const int w = t >> 6, wm = w & 1, wn = w >> 1;
  const bool vmode = bid >= 1024;
  int m0, n0;
  const bf16 *A, *BT;
  if (!vmode) {
    int xcd = bid & 7, idx = bid >> 3;
    m0 = (idx >> 1) * 128;
    n0 = (xcd * 2 + (idx & 1)) * 128;
    A = xb; BT = WT;
  } else {
    int b2 = bid - 1024;
    int xcd = b2 & 7, idx = b2 >> 3;
    m0 = (idx >> 3) * 128;
    n0 = (xcd * 8 + (idx & 7)) * 128;
    A = WT + (size_t)2048 * 1024; BT = xb;
  }
  f32x4 acc[4][4] = {};
  gemm_core(A, BT, m0, n0, As, Bs, acc);
  if (vmode) {
#pragma unroll
    for (int nt = 0; nt < 4; ++nt) {
      int sg = n0 + wn * 64 + nt * 16 + lm;
      size_t sb = (size_t)(sg >> 11) * 2097152 + (sg & 2047);
#pragma unroll
      for (int mt = 0; mt < 4; ++mt)
#pragma unroll
        for (int r = 0; r < 4; ++r) {
          int m = m0 + wm * 64 + mt * 16 + q * 4 + r;
          VTb[sb + (size_t)(m >> 6) * 131072 + (size_t)(m & 63) * 2048] =
              (bf16)(acc[mt][nt][r] + bias_all[2048 + m]);
        }
    }
  } else {
#pragma unroll
    for (int nt = 0; nt < 4; ++nt) {
      int col = n0 + wn * 64 + nt * 16 + lm;
      float bb = bias_all[col];
#pragma unroll
      for (int mt = 0; mt < 4; ++mt) {
        int row = m0 + wm * 64 + mt * 16 + q * 4;
#pragma unroll
        for (int r = 0; r < 4; ++r)
          QKb[(size_t)(row + r) * 2048 + col] = (bf16)(acc[mt][nt][r] + bb);
      }
    }
  }
}

// ---------------- out-proj GEMM (512 blocks, f32 out) ----------------
__global__ __launch_bounds__(256) void gemm_out(const bf16* __restrict__ after,
                                                const bf16* __restrict__ WoT,
                                                const float* __restrict__ bo,
                                                float* __restrict__ out) {
  __shared__ __align__(16) bf16 As[128 * 64];
  __shared__ __align__(16) bf16 Bs[128 * 64];
  const int bid = blockIdx.x;
  const int t = threadIdx.x;
  const int l = t & 63, q = l >> 4, lm = l & 15;
  const int w = t >> 6, wm = w & 1, wn = w >> 1;
  const int xcd = bid & 7, idx = bid >> 3;
  const int n0 = xcd * 128, m0 = idx * 128;
  f32x4 acc[4][4] = {};
  gemm_core(after, WoT, m0, n0, As, Bs, acc);
#pragma unroll
  for (int nt = 0; nt < 4; ++nt) {
    int col = n0 + wn * 64 + nt * 16 + lm;
    float bb = bo[col];
#pragma unroll
    for (int mt = 0; mt < 4; ++mt) {
      int row = m0 + wm * 64 + mt * 16 + q * 4;
#pragma unroll
      for (int r = 0; r < 4; ++r)
        out[(size_t)(row + r) * 1024 + col] = acc[mt][nt][r] + bb;
    }
  }
}

// ---------------- flash attention: 32x32 MFMA, register-only P ----------------
__global__ __launch_bounds__(256, 4) void attn(const bf16* __restrict__ QK,
                                               const bf16* __restrict__ VT,
                                               bf16* __restrict__ after) {
  __shared__ __align__(16) bf16 Ks[2][64 * 64];
  __shared__ __align__(16) bf16 Vs[2][64 * 64];
  const int t = threadIdx.x;
  const int l = t & 63, w = t >> 6;
  const int lh = l & 31, H = l >> 5;          // half-wave id
  const int f = blockIdx.x;
  const int bn = (f & 7) | ((f >> 7) << 3);   // XCD keeps one bn's K/V in L2
  const int s0 = ((f >> 3) & 15) * 128;
  const int b = bn >> 4, n = bn & 15;
  const bf16* Qb = QK + (size_t)(b * 2048) * 2048 + n * 64;
  const bf16* Kb = Qb + 1024;
  const bf16* Vtb = VT + (size_t)bn * 131072;
  int ro[4], co[4];
#pragma unroll
  for (int i = 0; i < 4; ++i) {
    int o = i * 256 + t;
    ro[i] = o >> 3;
    co[i] = ((o & 7) ^ ((o >> 3) & 7)) << 3;
  }
  const int lbase = (t & 192) * 8;
  // stage Q (16KB) through the two K buffers; B-operand frags: Q[s=w*32+lh][d]
  bf16* Kflat = &Ks[0][0];
#pragma unroll
  for (int i = 0; i < 4; ++i)
    g2l16(&Qb[(size_t)(s0 + ro[i]) * 2048 + co[i]], Kflat + i * 2048 + lbase);
  __syncthreads();
  bf16x8 qb[4];
#pragma unroll
  for (int ks = 0; ks < 4; ++ks)
    qb[ks] = *(const bf16x8*)&Kflat[sw(w * 32 + lh, ks * 16 + H * 8)];
  __syncthreads();
  // prologue DMA into buf 0
#pragma unroll
  for (int i = 0; i < 2; ++i) {
    g2l16(&Kb[(size_t)ro[i] * 2048 + co[i]], &Ks[0][i * 2048 + lbase]);
    g2l16(&Vtb[(size_t)ro[i] * 2048 + co[i]], &Vs[0][i * 2048 + lbase]);
  }
  f32x16 o_acc[2] = {};
  float rs = 0.f;                             // denominator partial for s = s0+w*32+lh
  for (int rd = 0; rd < 32; ++rd) {
    const int cur = rd & 1;
    __syncthreads();                          // buf[cur] drained; buf[cur^1] free
    if (rd < 31) {
      int t0n = (rd + 1) * 64, nb = cur ^ 1;
#pragma unroll
      for (int i = 0; i < 2; ++i) {
        g2l16(&Kb[(size_t)(t0n + ro[i]) * 2048 + co[i]], &Ks[nb][i * 2048 + lbase]);
        g2l16(&Vtb[(size_t)ro[i] * 2048 + t0n + co[i]], &Vs[nb][i * 2048 + lbase]);
      }
    }
#pragma unroll
    for (int tt = 0; tt < 2; ++tt) {
      // S^T tile (t = tt*32.., s = w*32..): A=K[t][d], B=Q[s][d]
      f32x16 sc = {};
#pragma unroll
      for (int ks = 0; ks < 4; ++ks) {
        bf16x8 kb = *(const bf16x8*)&Ks[cur][sw(tt * 32 + lh, ks * 16 + H * 8)];
        sc = __builtin_amdgcn_mfma_f32_32x32x16_bf16(kb, qb[ks], sc, 0, 0, 0);
      }
      // exp2 + pack; reg r holds row t = (r&3)+8*(r>>2)+4H, col s=lh
      u32 pk[8], xx[8];
#pragma unroll
      for (int i = 0; i < 8; ++i) {
        float p0 = __builtin_amdgcn_exp2f(sc[2 * i]);
        float p1 = __builtin_amdgcn_exp2f(sc[2 * i + 1]);
        rs += p0 + p1;
        pk[i] = pkbf(p0, p1);
      }
#pragma unroll
      for (int i = 0; i < 8; ++i) xx[i] = __shfl_xor((int)pk[i], 32);
      // PV: A(m=s, k=t) assembled in-register from pk/xx
#pragma unroll
      for (int ks2 = 0; ks2 < 2; ++ks2) {
        u32x4 av;
        av[0] = H ? xx[ks2 * 4 + 2] : pk[ks2 * 4 + 0];
        av[1] = H ? xx[ks2 * 4 + 3] : pk[ks2 * 4 + 1];
        av[2] = H ? pk[ks2 * 4 + 2] : xx[ks2 * 4 + 0];
        av[3] = H ? pk[ks2 * 4 + 3] : xx[ks2 * 4 + 1];
        bf16x8 pa = __builtin_bit_cast(bf16x8, av);
#pragma unroll
        for (int ht = 0; ht < 2; ++ht) {
          bf16x8 vb = *(const bf16x8*)&Vs[cur][sw(ht * 32 + lh, tt * 32 + ks2 * 16 + H * 8)];
          o_acc[ht] = __builtin_amdgcn_mfma_f32_32x32x16_bf16(pa, vb, o_acc[ht], 0, 0, 0);
        }
      }
    }
  }
  // epilogue: complete denominator, normalize, store
  rs += __shfl_xor(rs, 32);
  float inv = 1.f / rs;
#pragma unroll
  for (int r = 0; r < 16; ++r) {
    int sl = (r & 3) + 8 * (r >> 2) + 4 * H;   // local s of this reg-row
    float invr = __shfl(inv, sl);
    size_t base = (size_t)(b * 2048 + s0 + w * 32 + sl) * 1024 + n * 64;
#pragma unroll
    for (int ht = 0; ht < 2; ++ht)
      after[base + ht * 32 + lh] = (bf16)(o_acc[ht][r] * invr);
  }
}

// ---------------- launch ----------------
extern "C" void kernel_launch(void* const* d_in, const int* in_sizes, int n_in,
                              void* d_out, int out_size, void* d_ws, size_t ws_size,
                              hipStream_t stream) {
  const float* x  = (const float*)d_in[0];
  const float* Wq = (const float*)d_in[1];
  const float* bq = (const float*)d_in[2];
  const float* Wk = (const float*)d_in[3];
  const float* bk = (const float*)d_in[4];
  const float* Wv = (const float*)d_in[5];
  const float* bv = (const float*)d_in[6];
  const float* Wo = (const float*)d_in[7];
  const float* bo = (const float*)d_in[8];
  float* out = (float*)d_out;

  bf16* WT_all    = (bf16*)d_ws;                         // [3072 nh][1024 d]
  bf16* WoT       = WT_all + (size_t)3072 * 1024;        // [1024 d][1024 c]
  float* bias_all = (float*)(WoT + (size_t)1024 * 1024); // [3072]
  bf16* xb        = (bf16*)(bias_all + 4096);            // [8192][1024]
  bf16* QKb       = xb + (size_t)BS * Dd;                // [8192][2048] (Q|K)
  bf16* VTb       = QKb + (size_t)BS * 2048;             // [64 bn][64 h][2048 s]
  bf16* after     = VTb + (size_t)Bb * NH * HD * Ss;     // [8192][1024]

  prep<<<dim3(8192, 2), dim3(256), 0, stream>>>(x, xb, Wq, Wk, Wv, Wo, bq, bk, bv,
                                                WT_all, WoT, bias_all);
  gemm_qkv<<<dim3(1536), dim3(256), 0, stream>>>(xb, WT_all, bias_all, QKb, VTb);
  attn<<<dim3(1024), dim3(256), 0, stream>>>(QKb, VTb, after);
  gemm_out<<<dim3(512), dim3(256), 0, stream>>>(after, WoT, bo, out);
}

// Round 8
// 274.713 us; speedup vs baseline: 1.0395x; 1.0395x over previous
//
#include <hip/hip_runtime.h>

typedef __bf16 bf16;
typedef bf16 bf16x8 __attribute__((ext_vector_type(8)));
typedef bf16 bf16x4 __attribute__((ext_vector_type(4)));
typedef bf16 bf16x2 __attribute__((ext_vector_type(2)));
typedef float f32x4 __attribute__((ext_vector_type(4)));
typedef float f32x16 __attribute__((ext_vector_type(16)));
typedef unsigned int u32;
typedef u32 u32x4 __attribute__((ext_vector_type(4)));
typedef int i32x2 __attribute__((ext_vector_type(2)));

constexpr int Bb = 4, Ss = 2048, Dd = 1024, NH = 16, HD = 64;
constexpr int BS = Bb * Ss;          // 8192
constexpr float CSC = 0.18033688011112042f;  // (1/sqrt(64)) * log2(e), folded into Wq

__device__ __forceinline__ int sw(int row, int col) {
  return (row << 6) + (col ^ ((row & 7) << 3));
}
__device__ __forceinline__ int sw128(int row, int col) {
  return (row << 7) + (col ^ ((row & 7) << 3));
}

__device__ __forceinline__ void g2l16(const bf16* g, bf16* l) {
  __builtin_amdgcn_global_load_lds(
      (const __attribute__((address_space(1))) void*)g,
      (__attribute__((address_space(3))) void*)l, 16, 0, 0);
}

__device__ __forceinline__ u32 pkbf(float a, float b) {
  bf16x2 v = {(bf16)a, (bf16)b};
  return __builtin_bit_cast(u32, v);
}

// ---------------- prep: x cvt + weight transposes + bias ----------------
__global__ void prep(const float* __restrict__ x, bf16* __restrict__ xb,
                     const float* __restrict__ Wq, const float* __restrict__ Wk,
                     const float* __restrict__ Wv, const float* __restrict__ Wo,
                     const float* __restrict__ bq, const float* __restrict__ bk,
                     const float* __restrict__ bv,
                     bf16* __restrict__ WT_all, bf16* __restrict__ WoT,
                     float* __restrict__ bias_all) {
  __shared__ bf16 Ts[64 * 72];
  const int t = threadIdx.x;
  if (blockIdx.y == 0) {           // x: f32 -> bf16 (8192 blocks)
    int o = (blockIdx.x * 256 + t) * 4;
    f32x4 v = *(const f32x4*)&x[o];
    bf16x4 r = {(bf16)v[0], (bf16)v[1], (bf16)v[2], (bf16)v[3]};
    *(bf16x4*)&xb[o] = r;
    return;
  }
  if (blockIdx.x > 1024) return;
  if (blockIdx.x == 1024) {
    for (int j = t; j < 3072; j += 256) {
      int s2 = j >> 10;
      const float* bb = (s2 == 0) ? bq : (s2 == 1) ? bk : bv;
      bias_all[j] = bb[j & 1023] * (s2 == 0 ? CSC : 1.0f);
    }
    return;
  }
  const int sel = blockIdx.x >> 8, bx = blockIdx.x & 255;
  if (sel < 3) {
    const float* W = (sel == 0) ? Wq : (sel == 1) ? Wk : Wv;
    float scale = (sel == 0) ? CSC : 1.0f;
    int head = bx >> 4, dt = bx & 15;
    const float* src = W + head * 65536 + dt * 64 * 64;   // [64 d][64 h]
#pragma unroll
    for (int i = 0; i < 4; ++i) {
      int idx = i * 256 + t;
      int dr = idx >> 4, hc = (idx & 15) * 4;
      f32x4 v = *(const f32x4*)&src[dr * 64 + hc];
#pragma unroll
      for (int k = 0; k < 4; ++k) Ts[(hc + k) * 72 + dr] = (bf16)(v[k] * scale);
    }
    __syncthreads();
    bf16* dst = WT_all + (size_t)sel * 1048576 + (size_t)(head * 64) * 1024 + dt * 64;
#pragma unroll
    for (int i = 0; i < 2; ++i) {
      int idx = i * 256 + t;
      int hr = idx >> 3, ch = (idx & 7) * 8;
      *(bf16x8*)&dst[(size_t)hr * 1024 + ch] = *(const bf16x8*)&Ts[hr * 72 + ch];
    }
  } else {
    int ct = bx >> 4, dt = bx & 15;
    const float* src = Wo + (size_t)(ct * 64) * 1024 + dt * 64;
#pragma unroll
    for (int i = 0; i < 4; ++i) {
      int idx = i * 256 + t;
      int cr = idx >> 4, dc = (idx & 15) * 4;
      f32x4 v = *(const f32x4*)&src[(size_t)cr * 1024 + dc];
#pragma unroll
      for (int k = 0; k < 4; ++k) Ts[(dc + k) * 72 + cr] = (bf16)v[k];
    }
    __syncthreads();
    bf16* dst = WoT + (size_t)(dt * 64) * 1024 + ct * 64;
#pragma unroll
    for (int i = 0; i < 2; ++i) {
      int idx = i * 256 + t;
      int dr = idx >> 3, ch = (idx & 7) * 8;
      *(bf16x8*)&dst[(size_t)dr * 1024 + ch] = *(const bf16x8*)&Ts[dr * 72 + ch];
    }
  }
}

// ---------------- shared 128x128 K=1024 MFMA core ----------------
__device__ __forceinline__ void gemm_core(const bf16* __restrict__ A,
                                          const bf16* __restrict__ BT,
                                          int m0, int n0, bf16* As, bf16* Bs,
                                          f32x4 (&acc)[4][4]) {
  const int t = threadIdx.x;
  const int l = t & 63, q = l >> 4, lm = l & 15;
  const int w = t >> 6, wm = w & 1, wn = w >> 1;
  int ro[4], co[4];
#pragma unroll
  for (int i = 0; i < 4; ++i) {
    int o = i * 256 + t;
    ro[i] = o >> 3;
    co[i] = ((o & 7) ^ ((o >> 3) & 7)) << 3;
  }
  const int lbase = (t & 192) * 8;
  for (int k0 = 0; k0 < 1024; k0 += 64) {
    __syncthreads();
#pragma unroll
    for (int i = 0; i < 4; ++i)
      g2l16(&A[(size_t)(m0 + ro[i]) * 1024 + k0 + co[i]], &As[i * 2048 + lbase]);
#pragma unroll
    for (int i = 0; i < 4; ++i)
      g2l16(&BT[(size_t)(n0 + ro[i]) * 1024 + k0 + co[i]], &Bs[i * 2048 + lbase]);
    __syncthreads();
#pragma unroll
    for (int kh = 0; kh < 2; ++kh) {
      bf16x8 a[4], b[4];
#pragma unroll
      for (int i = 0; i < 4; ++i)
        a[i] = *(const bf16x8*)&As[sw(wm * 64 + i * 16 + lm, kh * 32 + q * 8)];
#pragma unroll
      for (int i = 0; i < 4; ++i)
        b[i] = *(const bf16x8*)&Bs[sw(wn * 64 + i * 16 + lm, kh * 32 + q * 8)];
#pragma unroll
      for (int mt = 0; mt < 4; ++mt)
#pragma unroll
        for (int nt = 0; nt < 4; ++nt)
          acc[mt][nt] = __builtin_amdgcn_mfma_f32_16x16x32_bf16(a[mt], b[nt], acc[mt][nt], 0, 0, 0);
    }
  }
}

// ---------------- fused QK + V GEMM (1536 blocks) ----------------
__global__ __launch_bounds__(256) void gemm_qkv(const bf16* __restrict__ xb,
                                                const bf16* __restrict__ WT,
                                                const float* __restrict__ bias_all,
                                                bf16* __restrict__ QKb,
                                                bf16* __restrict__ VTb) {
  __shared__ __align__(16) bf16 SMEM[2 * 128 * 64];
  bf16* As = SMEM;
  bf16* Bs = SMEM + 128 * 64;
  const int bid = blockIdx.x;
  const int t = threadIdx.x;
  const int l = t & 63, q = l >> 4, lm = l & 15;
  const int w = t >> 6, wm = w & 1, wn = w >> 1;
  const bool vmode = bid >= 1024;
  int m0, n0;
  const bf16 *A, *BT;
  if (!vmode) {
    int xcd = bid & 7, idx = bid >> 3;
    m0 = (idx >> 1) * 128;
    n0 = (xcd * 2 + (idx & 1)) * 128;
    A = xb; BT = WT;
  } else {
    int b2 = bid - 1024;
    int xcd = b2 & 7, idx = b2 >> 3;
    m0 = (idx >> 3) * 128;
    n0 = (xcd * 8 + (idx & 7)) * 128;
    A = WT + (size_t)2048 * 1024; BT = xb;
  }
  f32x4 acc[4][4] = {};
  gemm_core(A, BT, m0, n0, As, Bs, acc);
  if (vmode) {
    // stage C-tile (m=nh 128, n=s 128) in LDS, then write coalesced VT rows
    __syncthreads();
#pragma unroll
    for (int nt = 0; nt < 4; ++nt) {
      int sl = wn * 64 + nt * 16 + lm;
#pragma unroll
      for (int mt = 0; mt < 4; ++mt) {
        int ml = wm * 64 + mt * 16 + q * 4;
#pragma unroll
        for (int r = 0; r < 4; ++r)
          SMEM[sw128(ml + r, sl)] = (bf16)(acc[mt][nt][r] + bias_all[2048 + m0 + ml + r]);
      }
    }
    __syncthreads();
    int hh = t >> 1, half = (t & 1) * 64;
    int m = m0 + hh;
    size_t gb = (size_t)((n0 >> 11) * 16 + (m >> 6)) * 131072 +
                (size_t)(m & 63) * 2048 + (n0 & 2047) + half;
#pragma unroll
    for (int k = 0; k < 8; ++k)
      *(bf16x8*)&VTb[gb + k * 8] = *(const bf16x8*)&SMEM[sw128(hh, half + k * 8)];
  } else {
#pragma unroll
    for (int nt = 0; nt < 4; ++nt) {
      int col = n0 + wn * 64 + nt * 16 + lm;
      float bb = bias_all[col];
#pragma unroll
      for (int mt = 0; mt < 4; ++mt) {
        int row = m0 + wm * 64 + mt * 16 + q * 4;
#pragma unroll
        for (int r = 0; r < 4; ++r)
          QKb[(size_t)(row + r) * 2048 + col] = (bf16)(acc[mt][nt][r] + bb);
      }
    }
  }
}

// ---------------- out-proj GEMM (512 blocks, f32 out) ----------------
__global__ __launch_bounds__(256) void gemm_out(const bf16* __restrict__ after,
                                                const bf16* __restrict__ WoT,
                                                const float* __restrict__ bo,
                                                float* __restrict__ out) {
  __shared__ __align__(16) bf16 SMEM[2 * 128 * 64];
  const int bid = blockIdx.x;
  const int t = threadIdx.x;
  const int l = t & 63, q = l >> 4, lm = l & 15;
  const int w = t >> 6, wm = w & 1, wn = w >> 1;
  const int xcd = bid & 7, idx = bid >> 3;
  const int n0 = xcd * 128, m0 = idx * 128;
  f32x4 acc[4][4] = {};
  gemm_core(after, WoT, m0, n0, SMEM, SMEM + 128 * 64, acc);
#pragma unroll
  for (int nt = 0; nt < 4; ++nt) {
    int col = n0 + wn * 64 + nt * 16 + lm;
    float bb = bo[col];
#pragma unroll
    for (int mt = 0; mt < 4; ++mt) {
      int row = m0 + wm * 64 + mt * 16 + q * 4;
#pragma unroll
      for (int r = 0; r < 4; ++r)
        out[(size_t)(row + r) * 1024 + col] = acc[mt][nt][r] + bb;
    }
  }
}

// ---------------- flash attention: 32x32 MFMA, register-only P ----------------
__global__ __launch_bounds__(256, 4) void attn(const bf16* __restrict__ QK,
                                               const bf16* __restrict__ VT,
                                               bf16* __restrict__ after) {
  __shared__ __align__(16) bf16 Ks[2][64 * 64];
  __shared__ __align__(16) bf16 Vs[2][64 * 64];
  const int t = threadIdx.x;
  const int l = t & 63, w = t >> 6;
  const int lh = l & 31, H = l >> 5;          // half-wave id
  const int f = blockIdx.x;
  const int bn = (f & 7) | ((f >> 7) << 3);   // XCD keeps one bn's K/V in L2
  const int s0 = ((f >> 3) & 15) * 128;
  const int b = bn >> 4, n = bn & 15;
  const bf16* Qb = QK + (size_t)(b * 2048) * 2048 + n * 64;
  const bf16* Kb = Qb + 1024;
  const bf16* Vtb = VT + (size_t)bn * 131072;
  int ro[4], co[4];
#pragma unroll
  for (int i = 0; i < 4; ++i) {
    int o = i * 256 + t;
    ro[i] = o >> 3;
    co[i] = ((o & 7) ^ ((o >> 3) & 7)) << 3;
  }
  const int lbase = (t & 192) * 8;
  // stage Q (16KB) through the two K buffers; B-operand frags: Q[s=w*32+lh][d]
  bf16* Kflat = &Ks[0][0];
#pragma unroll
  for (int i = 0; i < 4; ++i)
    g2l16(&Qb[(size_t)(s0 + ro[i]) * 2048 + co[i]], Kflat + i * 2048 + lbase);
  __syncthreads();
  bf16x8 qb[4];
#pragma unroll
  for (int ks = 0; ks < 4; ++ks)
    qb[ks] = *(const bf16x8*)&Kflat[sw(w * 32 + lh, ks * 16 + H * 8)];
  __syncthreads();
  // prologue DMA into buf 0
#pragma unroll
  for (int i = 0; i < 2; ++i) {
    g2l16(&Kb[(size_t)ro[i] * 2048 + co[i]], &Ks[0][i * 2048 + lbase]);
    g2l16(&Vtb[(size_t)ro[i] * 2048 + co[i]], &Vs[0][i * 2048 + lbase]);
  }
  f32x16 o_acc[2] = {};
  float rs = 0.f;                             // denominator partial for s = s0+w*32+lh
  for (int rd = 0; rd < 32; ++rd) {
    const int cur = rd & 1;
    __syncthreads();                          // buf[cur] drained; buf[cur^1] free
    if (rd < 31) {
      int t0n = (rd + 1) * 64, nb = cur ^ 1;
#pragma unroll
      for (int i = 0; i < 2; ++i) {
        g2l16(&Kb[(size_t)(t0n + ro[i]) * 2048 + co[i]], &Ks[nb][i * 2048 + lbase]);
        g2l16(&Vtb[(size_t)ro[i] * 2048 + t0n + co[i]], &Vs[nb][i * 2048 + lbase]);
      }
    }
#pragma unroll
    for (int tt = 0; tt < 2; ++tt) {
      // S^T tile (t = tt*32.., s = w*32..): A=K[t][d], B=Q[s][d]
      f32x16 sc = {};
#pragma unroll
      for (int ks = 0; ks < 4; ++ks) {
        bf16x8 kb = *(const bf16x8*)&Ks[cur][sw(tt * 32 + lh, ks * 16 + H * 8)];
        sc = __builtin_amdgcn_mfma_f32_32x32x16_bf16(kb, qb[ks], sc, 0, 0, 0);
      }
      // exp2 + pack; reg r holds row t = (r&3)+8*(r>>2)+4H, col s=lh
      u32 pk[8];
#pragma unroll
      for (int i = 0; i < 8; ++i) {
        float p0 = __builtin_amdgcn_exp2f(sc[2 * i]);
        float p1 = __builtin_amdgcn_exp2f(sc[2 * i + 1]);
        rs += p0 + p1;
        pk[i] = pkbf(p0, p1);
      }
      // PV: A(m=s, k=t) assembled via cross-half permlane swaps (VALU, no LDS)
#pragma unroll
      for (int ks2 = 0; ks2 < 2; ++ks2) {
        u32x4 av;
#if __has_builtin(__builtin_amdgcn_permlane32_swap)
        i32x2 sA = __builtin_amdgcn_permlane32_swap((int)pk[ks2 * 4 + 0], (int)pk[ks2 * 4 + 2],
                                                    false, false);
        i32x2 sB = __builtin_amdgcn_permlane32_swap((int)pk[ks2 * 4 + 1], (int)pk[ks2 * 4 + 3],
                                                    false, false);
        av[0] = (u32)sA[0]; av[1] = (u32)sB[0]; av[2] = (u32)sA[1]; av[3] = (u32)sB[1];
#else
        u32 xx[4];
        xx[0] = __shfl_xor((int)pk[ks2 * 4 + 0], 32);
        xx[1] = __shfl_xor((int)pk[ks2 * 4 + 1], 32);
        xx[2] = __shfl_xor((int)pk[ks2 * 4 + 2], 32);
        xx[3] = __shfl_xor((int)pk[ks2 * 4 + 3], 32);
        av[0] = H ? xx[2] : pk[ks2 * 4 + 0];
        av[1] = H ? xx[3] : pk[ks2 * 4 + 1];
        av[2] = H ? pk[ks2 * 4 + 2] : xx[0];
        av[3] = H ? pk[ks2 * 4 + 3] : xx[1];
#endif
        bf16x8 pa = __builtin_bit_cast(bf16x8, av);
#pragma unroll
        for (int ht = 0; ht < 2; ++ht) {
          bf16x8 vb = *(const bf16x8*)&Vs[cur][sw(ht * 32 + lh, tt * 32 + ks2 * 16 + H * 8)];
          o_acc[ht] = __builtin_amdgcn_mfma_f32_32x32x16_bf16(pa, vb, o_acc[ht], 0, 0, 0);
        }
      }
    }
  }
  // epilogue: complete denominator, normalize, store
  rs += __shfl_xor(rs, 32);
  float inv = 1.f / rs;
#pragma unroll
  for (int r = 0; r < 16; ++r) {
    int sl = (r & 3) + 8 * (r >> 2) + 4 * H;   // local s of this reg-row
    float invr = __shfl(inv, sl);
    size_t base = (size_t)(b * 2048 + s0 + w * 32 + sl) * 1024 + n * 64;
#pragma unroll
    for (int ht = 0; ht < 2; ++ht)
      after[base + ht * 32 + lh] = (bf16)(o_acc[ht][r] * invr);
  }
}

// ---------------- launch ----------------
extern "C" void kernel_launch(void* const* d_in, const int* in_sizes, int n_in,
                              void* d_out, int out_size, void* d_ws, size_t ws_size,
                              hipStream_t stream) {
  const float* x  = (const float*)d_in[0];
  const float* Wq = (const float*)d_in[1];
  const float* bq = (const float*)d_in[2];
  const float* Wk = (const float*)d_in[3];
  const float* bk = (const float*)d_in[4];
  const float* Wv = (const float*)d_in[5];
  const float* bv = (const float*)d_in[6];
  const float* Wo = (const float*)d_in[7];
  const float* bo = (const float*)d_in[8];
  float* out = (float*)d_out;

  bf16* WT_all    = (bf16*)d_ws;                         // [3072 nh][1024 d]
  bf16* WoT       = WT_all + (size_t)3072 * 1024;        // [1024 d][1024 c]
  float* bias_all = (float*)(WoT + (size_t)1024 * 1024); // [3072]
  bf16* xb        = (bf16*)(bias_all + 4096);            // [8192][1024]
  bf16* QKb       = xb + (size_t)BS * Dd;                // [8192][2048] (Q|K)
  bf16* VTb       = QKb + (size_t)BS * 2048;             // [64 bn][64 h][2048 s]
  bf16* after     = VTb + (size_t)Bb * NH * HD * Ss;     // [8192][1024]

  prep<<<dim3(8192, 2), dim3(256), 0, stream>>>(x, xb, Wq, Wk, Wv, Wo, bq, bk, bv,
                                                WT_all, WoT, bias_all);
  gemm_qkv<<<dim3(1536), dim3(256), 0, stream>>>(xb, WT_all, bias_all, QKb, VTb);
  attn<<<dim3(1024), dim3(256), 0, stream>>>(QKb, VTb, after);
  gemm_out<<<dim3(512), dim3(256), 0, stream>>>(after, WoT, bo, out);
}